// Round 1
// baseline (327.581 us; speedup 1.0000x reference)
//
#include <hip/hip_runtime.h>
#include <hip/hip_bf16.h>
#include <stdint.h>

#define D_MODEL 1024
#define NHEAD   16
#define DH      64

typedef __attribute__((ext_vector_type(8))) short bf16x8;
typedef __attribute__((ext_vector_type(4))) float f32x4;

__device__ __forceinline__ ushort f2bf(float f) {
    __hip_bfloat16 h = __float2bfloat16(f);
    return *reinterpret_cast<ushort*>(&h);
}

__device__ __forceinline__ void gload_lds16(const void* g, void* l) {
    __builtin_amdgcn_global_load_lds(
        (const __attribute__((address_space(1))) void*)g,
        (__attribute__((address_space(3))) void*)l, 16, 0, 0);
}

// Load 8 contiguous fp32, convert to bf16x8 in-register.
__device__ __forceinline__ bf16x8 load8f(const float* p) {
    const float4 a = *(const float4*)p;
    const float4 b = *(const float4*)(p + 4);
    bf16x8 r;
    r[0] = (short)f2bf(a.x); r[1] = (short)f2bf(a.y);
    r[2] = (short)f2bf(a.z); r[3] = (short)f2bf(a.w);
    r[4] = (short)f2bf(b.x); r[5] = (short)f2bf(b.y);
    r[6] = (short)f2bf(b.z); r[7] = (short)f2bf(b.w);
    return r;
}

// fp32 -> bf16 weight conversion: 4 matrices of 1M elements each.
__global__ __launch_bounds__(256) void cvt_w_kernel(
    const float* __restrict__ w0, const float* __restrict__ w1,
    const float* __restrict__ w2, const float* __restrict__ w3,
    ushort* __restrict__ out)
{
    const int g = blockIdx.x * 256 + threadIdx.x;   // group of 8 elems
    const int m = g >> 17;                          // 131072 groups / matrix
    const int off = (g & 131071) * 8;
    const float* src = (m == 0) ? w0 : (m == 1) ? w1 : (m == 2) ? w2 : w3;
    *(bf16x8*)(out + (size_t)m * 1048576 + off) = load8f(src + off);
}

// ---- shared GEMM epilogue helpers ----
__device__ __forceinline__ void storeC(float*  C, size_t i, float v) { C[i] = v; }
__device__ __forceinline__ void storeC(ushort* C, size_t i, float v) { C[i] = (short)f2bf(v); }

// C = X(MxK) @ Wb^T (Wb NxK bf16) + bias. A_F32: X is fp32 (reg-staged +
// convert); else X is bf16 ushort (global_load_lds). B always via
// global_load_lds.
//
// 2-phase software pipeline (T3 minimum recipe): double-buffered LDS;
// per K-step: issue NEXT tile's stage loads FIRST, then ds_read+MFMA on
// current buffer, then (fp32 path) convert+ds_write the prefetched A regs,
// then ONE barrier (drains vmcnt/lgkm). Load latency hides under MFMA —
// critical for out_proj which runs at 1 block/CU (no inter-block overlap).
template<bool A_F32, typename TX, typename TOUT>
__device__ __forceinline__ void gemm_core(
    const TX* __restrict__ X,
    const ushort* __restrict__ Wb,
    const float* __restrict__ Bias,
    TOUT* __restrict__ C,
    int M, int N, int K,
    short (*As)[4096], short (*Bs)[4096])
{
    const int tid  = threadIdx.x;
    const int w    = tid >> 6;
    const int lane = tid & 63;
    const int quad = lane >> 4;
    const int l15  = lane & 15;
    const int wr   = w >> 1, wc = w & 1;
    const int m0 = blockIdx.y * 128;
    const int n0 = blockIdx.x * 128;

    // fp32 A-path per-thread tile coords (fixed across K-steps)
    const int ar0 = tid >> 2,          ac0 = (tid & 3) * 8;
    const int ar1 = (256 + tid) >> 2,  ac1 = (tid & 3) * 8;

    f32x4 acc[4][4] = {};
    float4 aL0, aH0, aL1, aH1;   // prefetched fp32 A regs

    auto stageB = [&](int buf, int k0) {
        #pragma unroll
        for (int c = 0; c < 2; ++c) {
            int chunk = w * 2 + c;
            int row   = chunk * 16 + (lane >> 2);
            gload_lds16(Wb + (size_t)(n0 + row) * K + k0 + (lane & 3) * 8,
                        &Bs[buf][chunk * 512]);
        }
    };
    auto stageA_lds = [&](int buf, int k0) {
        #pragma unroll
        for (int c = 0; c < 2; ++c) {
            int chunk = w * 2 + c;
            int row   = chunk * 16 + (lane >> 2);
            gload_lds16((const ushort*)X + (size_t)(m0 + row) * K + k0 + (lane & 3) * 8,
                        &As[buf][chunk * 512]);
        }
    };
    auto issueA = [&](int k0) {
        const float* p0 = (const float*)X + (size_t)(m0 + ar0) * K + k0 + ac0;
        const float* p1 = (const float*)X + (size_t)(m0 + ar1) * K + k0 + ac1;
        aL0 = *(const float4*)p0; aH0 = *(const float4*)(p0 + 4);
        aL1 = *(const float4*)p1; aH1 = *(const float4*)(p1 + 4);
    };
    auto writeA = [&](int buf) {
        bf16x8 r0, r1;
        r0[0] = (short)f2bf(aL0.x); r0[1] = (short)f2bf(aL0.y);
        r0[2] = (short)f2bf(aL0.z); r0[3] = (short)f2bf(aL0.w);
        r0[4] = (short)f2bf(aH0.x); r0[5] = (short)f2bf(aH0.y);
        r0[6] = (short)f2bf(aH0.z); r0[7] = (short)f2bf(aH0.w);
        r1[0] = (short)f2bf(aL1.x); r1[1] = (short)f2bf(aL1.y);
        r1[2] = (short)f2bf(aL1.z); r1[3] = (short)f2bf(aL1.w);
        r1[4] = (short)f2bf(aH1.x); r1[5] = (short)f2bf(aH1.y);
        r1[6] = (short)f2bf(aH1.z); r1[7] = (short)f2bf(aH1.w);
        *(bf16x8*)&As[buf][ar0 * 32 + ac0] = r0;
        *(bf16x8*)&As[buf][ar1 * 32 + ac1] = r1;
    };

    const int NT = K >> 5;

    // prologue: fill buffer 0
    if constexpr (A_F32) {
        issueA(0);
        stageB(0, 0);
        writeA(0);            // waits its vmcnt; B DMA drains at barrier
    } else {
        stageB(0, 0);
        stageA_lds(0, 0);
    }
    __syncthreads();

    int buf = 0;
    for (int t = 0; t < NT; ++t) {
        const bool more = (t + 1 < NT);
        const int k1 = (t + 1) << 5;
        if (more) {
            if constexpr (A_F32) {
                issueA(k1);           // A loads oldest -> writeA waits fewer
                stageB(buf ^ 1, k1);
            } else {
                stageB(buf ^ 1, k1);
                stageA_lds(buf ^ 1, k1);
            }
        }

        bf16x8 af[4], bfr[4];
        #pragma unroll
        for (int i = 0; i < 4; ++i)
            af[i] = *(const bf16x8*)&As[buf][(wr * 64 + i * 16 + l15) * 32 + quad * 8];
        #pragma unroll
        for (int j = 0; j < 4; ++j)
            bfr[j] = *(const bf16x8*)&Bs[buf][(wc * 64 + j * 16 + l15) * 32 + quad * 8];
        #pragma unroll
        for (int i = 0; i < 4; ++i)
            #pragma unroll
            for (int j = 0; j < 4; ++j)
                acc[i][j] = __builtin_amdgcn_mfma_f32_16x16x32_bf16(af[i], bfr[j], acc[i][j], 0, 0, 0);

        if (more) {
            if constexpr (A_F32) writeA(buf ^ 1);   // convert after MFMA: loads had time to land
        }
        __syncthreads();   // single drain+barrier per K-step
        buf ^= 1;
    }

    float bias[4];
    #pragma unroll
    for (int j = 0; j < 4; ++j)
        bias[j] = Bias[n0 + wc * 64 + j * 16 + l15];

    #pragma unroll
    for (int i = 0; i < 4; ++i) {
        int row = m0 + wr * 64 + i * 16 + quad * 4;
        #pragma unroll
        for (int j = 0; j < 4; ++j) {
            int col = n0 + wc * 64 + j * 16 + l15;
            #pragma unroll
            for (int r = 0; r < 4; ++r)
                storeC(C, (size_t)(row + r) * N + col, acc[i][j][r] + bias[j]);
        }
    }
}

__global__ __launch_bounds__(256) void qkv_proj_kernel(
    const float* __restrict__ Qin, const float* __restrict__ Kin,
    const float* __restrict__ Vin,
    const ushort* __restrict__ Wb,
    const float* __restrict__ Bq, const float* __restrict__ Bk,
    const float* __restrict__ Bv,
    ushort* qo, ushort* ko, ushort* vo, int L)
{
    __shared__ short As[2][4096];
    __shared__ short Bs[2][4096];
    const int z = blockIdx.z;
    const float *X, *B; ushort* C;
    if (z == 0)      { X = Qin; B = Bq; C = qo; }
    else if (z == 1) { X = Kin; B = Bk; C = ko; }
    else             { X = Vin; B = Bv; C = vo; }
    gemm_core<true, float, ushort>(X, Wb + (size_t)z * 1048576, B, C,
                                   L, D_MODEL, D_MODEL, As, Bs);
}

__global__ __launch_bounds__(256) void out_proj_kernel(
    const ushort* __restrict__ Xa, const ushort* __restrict__ Wb,
    const float* __restrict__ Bo, float* out, int L)
{
    __shared__ short As[2][4096];
    __shared__ short Bs[2][4096];
    gemm_core<false, ushort, float>(Xa, Wb + (size_t)3 * 1048576, Bo, out,
                                    L, D_MODEL, D_MODEL, As, Bs);
}

// Flash attention, transposed-score form.
// R8 changes: (a) T14 async-stage — next K/V tile prefetched into regs
// during current tile's compute, LDS write after the barrier next iter;
// (b) T13 defer-max — skip alpha/rescale when tile max grew <= 8 in exp2
// domain (p bounded by 2^8, harmless for fp32 accum / bf16 P).
__global__ __launch_bounds__(512) void attn_kernel(
    const ushort* __restrict__ Qw,
    const ushort* __restrict__ Kw,
    const ushort* __restrict__ Vw,
    ushort* __restrict__ Ow, int L)
{
    __shared__ short Ks[64 * 64];
    __shared__ short Vs[64 * 64];
    __shared__ short Ps[8][16 * 64];

    const int tid  = threadIdx.x;
    const int w    = tid >> 6;
    const int lane = tid & 63;
    const int quad = lane >> 4;
    const int l15  = lane & 15;
    const int h    = blockIdx.y;
    const int q0   = blockIdx.x * 128;

    const ushort* qp = Qw + (size_t)(q0 + w * 16 + l15) * D_MODEL + h * DH + quad * 8;
    bf16x8 qf0 = *(const bf16x8*)(qp);
    bf16x8 qf1 = *(const bf16x8*)(qp + 32);

    const int kkey = tid >> 3;
    const int kc8  = tid & 7;
    const int vkey = lane;
    const int vdh  = w * 8;

    const int krswz0 = ((quad    ) ^ (l15 & 7)) * 8;
    const int krswz1 = ((quad + 4) ^ (l15 & 7)) * 8;

    f32x4 o[4] = {};
    float m_run = -3e38f, l_run = 0.f;
    const float csc = 0.125f * 1.44269504088896f;
    // defer-max: skip rescale while (mx - m_run)*csc <= 8  ->  mx <= m_run + 8/csc
    const float thr = 8.0f / csc;   // 44.36

    // prefetch tile 0 into regs
    const ushort* kptr = Kw + (size_t)kkey * D_MODEL + h * DH + kc8 * 8;
    const ushort* vptr = Vw + (size_t)vkey * D_MODEL + h * DH + vdh;
    bf16x8 kreg = *(const bf16x8*)kptr;
    bf16x8 vreg = *(const bf16x8*)vptr;

    for (int key0 = 0; key0 < L; key0 += 64) {
        __syncthreads();   // WAR: previous tile's LDS reads done
        *(bf16x8*)&Ks[kkey * 64 + ((kc8 ^ (kkey & 7)) * 8)] = kreg;
        #pragma unroll
        for (int i = 0; i < 8; ++i)
            Vs[(vdh + i) * 64 + (((vkey >> 3) ^ i) * 8) + (vkey & 7)] = vreg[i];
        __syncthreads();

        if (key0 + 64 < L) {        // issue next tile's loads; land during compute
            kptr += (size_t)64 * D_MODEL;
            vptr += (size_t)64 * D_MODEL;
            kreg = *(const bf16x8*)kptr;
            vreg = *(const bf16x8*)vptr;
        }

        f32x4 st[4];
        #pragma unroll
        for (int kt = 0; kt < 4; ++kt) {
            const int kr = (kt * 16 + l15) * 64;
            bf16x8 kf0 = *(const bf16x8*)&Ks[kr + krswz0];
            bf16x8 kf1 = *(const bf16x8*)&Ks[kr + krswz1];
            f32x4 z = {};
            z = __builtin_amdgcn_mfma_f32_16x16x32_bf16(kf0, qf0, z, 0, 0, 0);
            z = __builtin_amdgcn_mfma_f32_16x16x32_bf16(kf1, qf1, z, 0, 0, 0);
            st[kt] = z;
        }

        float mx = st[0][0];
        #pragma unroll
        for (int kt = 0; kt < 4; ++kt)
            #pragma unroll
            for (int r = 0; r < 4; ++r)
                mx = fmaxf(mx, st[kt][r]);
        mx = fmaxf(mx, __shfl_xor(mx, 16));
        mx = fmaxf(mx, __shfl_xor(mx, 32));

        if (!__all(mx <= m_run + thr)) {
            const float mnew  = fmaxf(m_run, mx);
            const float alpha = __builtin_amdgcn_exp2f((m_run - mnew) * csc);
            m_run = mnew;
            l_run *= alpha;
            float a[4];
            #pragma unroll
            for (int r = 0; r < 4; ++r)
                a[r] = __shfl(alpha, (lane & 48) | (quad * 4 + r));
            #pragma unroll
            for (int dt = 0; dt < 4; ++dt)
                #pragma unroll
                for (int r = 0; r < 4; ++r)
                    o[dt][r] *= a[r];
        }

        float rs = 0.f;
        #pragma unroll
        for (int kt = 0; kt < 4; ++kt) {
            float p0 = __builtin_amdgcn_exp2f((st[kt][0] - m_run) * csc);
            float p1 = __builtin_amdgcn_exp2f((st[kt][1] - m_run) * csc);
            float p2 = __builtin_amdgcn_exp2f((st[kt][2] - m_run) * csc);
            float p3 = __builtin_amdgcn_exp2f((st[kt][3] - m_run) * csc);
            rs += (p0 + p1) + (p2 + p3);
            uint2 pk;
            pk.x = (uint32_t)f2bf(p0) | ((uint32_t)f2bf(p1) << 16);
            pk.y = (uint32_t)f2bf(p2) | ((uint32_t)f2bf(p3) << 16);
            const int G = kt * 2 + (quad >> 1);
            *(uint2*)&Ps[w][l15 * 64 + ((G ^ (l15 & 7)) * 8) + (quad & 1) * 4] = pk;
        }
        rs += __shfl_xor(rs, 16);
        rs += __shfl_xor(rs, 32);
        l_run += rs;

        #pragma unroll
        for (int f = 0; f < 2; ++f) {
            bf16x8 pf = *(const bf16x8*)&Ps[w][l15 * 64 + (((f * 4 + quad) ^ (l15 & 7)) * 8)];
            #pragma unroll
            for (int dt = 0; dt < 4; ++dt) {
                bf16x8 vf = *(const bf16x8*)&Vs[(dt * 16 + l15) * 64 + (((f * 4 + quad) ^ (l15 & 7)) * 8)];
                o[dt] = __builtin_amdgcn_mfma_f32_16x16x32_bf16(pf, vf, o[dt], 0, 0, 0);
            }
        }
    }

    const float inv = 1.f / l_run;
    #pragma unroll
    for (int r = 0; r < 4; ++r) {
        const float linv = __shfl(inv, (lane & 48) | (quad * 4 + r));
        const int row = q0 + w * 16 + quad * 4 + r;
        #pragma unroll
        for (int dt = 0; dt < 4; ++dt) {
            int col = h * DH + dt * 16 + l15;
            Ow[(size_t)row * D_MODEL + col] = (short)f2bf(o[dt][r] * linv);
        }
    }
}

extern "C" void kernel_launch(void* const* d_in, const int* in_sizes, int n_in,
                              void* d_out, int out_size, void* d_ws, size_t ws_size,
                              hipStream_t stream) {
    const float* Q   = (const float*)d_in[0];
    const float* K   = (const float*)d_in[1];
    const float* V   = (const float*)d_in[2];
    const float* w_q = (const float*)d_in[3];
    const float* b_q = (const float*)d_in[4];
    const float* w_k = (const float*)d_in[5];
    const float* b_k = (const float*)d_in[6];
    const float* w_v = (const float*)d_in[7];
    const float* b_v = (const float*)d_in[8];
    const float* w_o = (const float*)d_in[9];
    const float* b_o = (const float*)d_in[10];
    float* out = (float*)d_out;

    const int L = in_sizes[0] / D_MODEL;   // 4096
    const size_t mat = (size_t)L * D_MODEL;

    // Memory plan (d_ws known-safe at 24 MB; d_out = 16 MB fp32):
    //   d_ws  [0, 8MB): Wb   — 4 bf16 weight matrices (wq,wk,wv,wo)
    //   d_ws  [8,16MB): a_ws — attention output (bf16)
    //   d_ws [16,24MB): v_ws — projected V (bf16)
    //   d_out [0, 8MB): q_ws; d_out [8,16MB): k_ws — dead before out_proj
    //   writes fp32 C over all of d_out (stream-ordered; fully rewritten).
    ushort* Wb   = (ushort*)d_ws;
    ushort* a_ws = (ushort*)d_ws + 4 * 1048576;
    ushort* v_ws = a_ws + mat;
    ushort* q_ws = (ushort*)d_out;
    ushort* k_ws = q_ws + mat;

    cvt_w_kernel<<<dim3(2048), dim3(256), 0, stream>>>(w_q, w_k, w_v, w_o, Wb);

    dim3 gqkv(D_MODEL / 128, L / 128, 3);
    qkv_proj_kernel<<<gqkv, dim3(256), 0, stream>>>(Q, K, V, Wb, b_q, b_k, b_v,
                                                    q_ws, k_ws, v_ws, L);
    dim3 gattn(L / 128, NHEAD);
    attn_kernel<<<gattn, dim3(512), 0, stream>>>(q_ws, k_ws, v_ws, a_ws, L);
    dim3 gout(D_MODEL / 128, L / 128);
    out_proj_kernel<<<gout, dim3(256), 0, stream>>>(a_ws, Wb, b_o, out, L);
}

// Round 2
// 317.868 us; speedup vs baseline: 1.0306x; 1.0306x over previous
//
#include <hip/hip_runtime.h>
#include <hip/hip_bf16.h>
#include <stdint.h>

#define D_MODEL 1024
#define NHEAD   16
#define DH      64

typedef __attribute__((ext_vector_type(8))) short bf16x8;
typedef __attribute__((ext_vector_type(4))) float f32x4;

__device__ __forceinline__ ushort f2bf(float f) {
    __hip_bfloat16 h = __float2bfloat16(f);
    return *reinterpret_cast<ushort*>(&h);
}

__device__ __forceinline__ void gload_lds16(const void* g, void* l) {
    __builtin_amdgcn_global_load_lds(
        (const __attribute__((address_space(1))) void*)g,
        (__attribute__((address_space(3))) void*)l, 16, 0, 0);
}

// Load 8 contiguous fp32, convert to bf16x8 in-register.
__device__ __forceinline__ bf16x8 load8f(const float* p) {
    const float4 a = *(const float4*)p;
    const float4 b = *(const float4*)(p + 4);
    bf16x8 r;
    r[0] = (short)f2bf(a.x); r[1] = (short)f2bf(a.y);
    r[2] = (short)f2bf(a.z); r[3] = (short)f2bf(a.w);
    r[4] = (short)f2bf(b.x); r[5] = (short)f2bf(b.y);
    r[6] = (short)f2bf(b.z); r[7] = (short)f2bf(b.w);
    return r;
}

// fp32 -> bf16 weight conversion: 4 matrices of 1M elements each.
__global__ __launch_bounds__(256) void cvt_w_kernel(
    const float* __restrict__ w0, const float* __restrict__ w1,
    const float* __restrict__ w2, const float* __restrict__ w3,
    ushort* __restrict__ out)
{
    const int g = blockIdx.x * 256 + threadIdx.x;   // group of 8 elems
    const int m = g >> 17;                          // 131072 groups / matrix
    const int off = (g & 131071) * 8;
    const float* src = (m == 0) ? w0 : (m == 1) ? w1 : (m == 2) ? w2 : w3;
    *(bf16x8*)(out + (size_t)m * 1048576 + off) = load8f(src + off);
}

// ---- shared GEMM epilogue helpers ----
__device__ __forceinline__ void storeC(float*  C, size_t i, float v) { C[i] = v; }
__device__ __forceinline__ void storeC(ushort* C, size_t i, float v) { C[i] = (short)f2bf(v); }

// C = X(MxK) @ Wb^T (Wb NxK bf16) + bias. A_F32: X is fp32 (explicit staging);
// else X is bf16 ushort (global_load_lds). B always via global_load_lds.
// R0 structure (2 barriers/K-step — proven best; 2-phase rewrite regressed,
// matching guide m99-m141). R2 adds XCD-aware block swizzle: each XCD owns
// 4 contiguous m-rows x all 8 n-cols, so X-tiles are fetched into ONE L2
// and W (2MB) is L2-resident per XCD.
template<bool A_F32, typename TX, typename TOUT>
__device__ __forceinline__ void gemm_core(
    const TX* __restrict__ X,
    const ushort* __restrict__ Wb,
    const float* __restrict__ Bias,
    TOUT* __restrict__ C,
    int M, int N, int K,
    short* As, short* Bs)
{
    const int tid  = threadIdx.x;
    const int w    = tid >> 6;
    const int lane = tid & 63;
    const int quad = lane >> 4;
    const int l15  = lane & 15;
    const int wr   = w >> 1, wc = w & 1;

    // XCD swizzle (bijective; identity if shape doesn't fit)
    int bx = blockIdx.x, by = blockIdx.y;
    if (gridDim.x == 8 && (gridDim.y & 7) == 0) {
        const int fid   = by * 8 + bx;
        const int xcd   = fid & 7;
        const int local = fid >> 3;
        const int rpx   = gridDim.y >> 3;
        by = xcd * rpx + (local >> 3);
        bx = local & 7;
    }
    const int m0 = by * 128;
    const int n0 = bx * 128;

    f32x4 acc[4][4] = {};

    for (int k0 = 0; k0 < K; k0 += 32) {
        __syncthreads();   // WAR on LDS tiles
        // B-tile: 8 chunks of 1 KB, 2 per wave, DMA direct to LDS.
        #pragma unroll
        for (int c = 0; c < 2; ++c) {
            int chunk = w * 2 + c;
            int row   = chunk * 16 + (lane >> 2);
            gload_lds16(Wb + (size_t)(n0 + row) * K + k0 + (lane & 3) * 8,
                        &Bs[chunk * 512]);
        }
        // A-tile
        if (A_F32) {
            #pragma unroll
            for (int c = 0; c < 2; ++c) {
                int idx = c * 256 + tid;
                int row = idx >> 2;
                int col = (idx & 3) * 8;
                *(bf16x8*)&As[row * 32 + col] =
                    load8f((const float*)X + (size_t)(m0 + row) * K + k0 + col);
            }
        } else {
            #pragma unroll
            for (int c = 0; c < 2; ++c) {
                int chunk = w * 2 + c;
                int row   = chunk * 16 + (lane >> 2);
                gload_lds16((const ushort*)X + (size_t)(m0 + row) * K + k0 + (lane & 3) * 8,
                            &As[chunk * 512]);
            }
        }
        __syncthreads();   // drains vmcnt (DMA) + lgkmcnt before use

        bf16x8 af[4], bfr[4];
        #pragma unroll
        for (int i = 0; i < 4; ++i)
            af[i] = *(const bf16x8*)&As[(wr * 64 + i * 16 + l15) * 32 + quad * 8];
        #pragma unroll
        for (int j = 0; j < 4; ++j)
            bfr[j] = *(const bf16x8*)&Bs[(wc * 64 + j * 16 + l15) * 32 + quad * 8];
        #pragma unroll
        for (int i = 0; i < 4; ++i)
            #pragma unroll
            for (int j = 0; j < 4; ++j)
                acc[i][j] = __builtin_amdgcn_mfma_f32_16x16x32_bf16(af[i], bfr[j], acc[i][j], 0, 0, 0);
    }

    float bias[4];
    #pragma unroll
    for (int j = 0; j < 4; ++j)
        bias[j] = Bias[n0 + wc * 64 + j * 16 + l15];

    #pragma unroll
    for (int i = 0; i < 4; ++i) {
        int row = m0 + wr * 64 + i * 16 + quad * 4;
        #pragma unroll
        for (int j = 0; j < 4; ++j) {
            int col = n0 + wc * 64 + j * 16 + l15;
            #pragma unroll
            for (int r = 0; r < 4; ++r)
                storeC(C, (size_t)(row + r) * N + col, acc[i][j][r] + bias[j]);
        }
    }
}

__global__ __launch_bounds__(256) void qkv_proj_kernel(
    const float* __restrict__ Qin, const float* __restrict__ Kin,
    const float* __restrict__ Vin,
    const ushort* __restrict__ Wb,
    const float* __restrict__ Bq, const float* __restrict__ Bk,
    const float* __restrict__ Bv,
    ushort* qo, ushort* ko, ushort* vo, int L)
{
    __shared__ short As[4096];
    __shared__ short Bs[4096];
    const int z = blockIdx.z;
    const float *X, *B; ushort* C;
    if (z == 0)      { X = Qin; B = Bq; C = qo; }
    else if (z == 1) { X = Kin; B = Bk; C = ko; }
    else             { X = Vin; B = Bv; C = vo; }
    gemm_core<true, float, ushort>(X, Wb + (size_t)z * 1048576, B, C,
                                   L, D_MODEL, D_MODEL, As, Bs);
}

__global__ __launch_bounds__(256) void out_proj_kernel(
    const ushort* __restrict__ Xa, const ushort* __restrict__ Wb,
    const float* __restrict__ Bo, float* out, int L)
{
    __shared__ short As[4096];
    __shared__ short Bs[4096];
    gemm_core<false, ushort, float>(Xa, Wb + (size_t)3 * 1048576, Bo, out,
                                    L, D_MODEL, D_MODEL, As, Bs);
}

// Flash attention, transposed-score form.
// R1: T14 async-stage (reg prefetch) + T13 defer-max  — kept (confirmed -18us).
// R2: K/V LDS double-buffer -> ONE barrier per tile (was 2). Grid-limited
// occupancy (2 blocks/CU) means the extra 16KB LDS is free.
__global__ __launch_bounds__(512) void attn_kernel(
    const ushort* __restrict__ Qw,
    const ushort* __restrict__ Kw,
    const ushort* __restrict__ Vw,
    ushort* __restrict__ Ow, int L)
{
    __shared__ short Ks[2][64 * 64];
    __shared__ short Vs[2][64 * 64];
    __shared__ short Ps[8][16 * 64];

    const int tid  = threadIdx.x;
    const int w    = tid >> 6;
    const int lane = tid & 63;
    const int quad = lane >> 4;
    const int l15  = lane & 15;
    const int h    = blockIdx.y;
    const int q0   = blockIdx.x * 128;

    const ushort* qp = Qw + (size_t)(q0 + w * 16 + l15) * D_MODEL + h * DH + quad * 8;
    bf16x8 qf0 = *(const bf16x8*)(qp);
    bf16x8 qf1 = *(const bf16x8*)(qp + 32);

    const int kkey = tid >> 3;
    const int kc8  = tid & 7;
    const int vkey = lane;
    const int vdh  = w * 8;

    const int krswz0 = ((quad    ) ^ (l15 & 7)) * 8;
    const int krswz1 = ((quad + 4) ^ (l15 & 7)) * 8;

    const int kwofs = kkey * 64 + ((kc8 ^ (kkey & 7)) * 8);

    f32x4 o[4] = {};
    float m_run = -3e38f, l_run = 0.f;
    const float csc = 0.125f * 1.44269504088896f;
    const float thr = 8.0f / csc;   // defer-max threshold (exp2 domain 8)

    const int NT = L >> 6;
    const ushort* kbase = Kw + (size_t)kkey * D_MODEL + h * DH + kc8 * 8;
    const ushort* vbase = Vw + (size_t)vkey * D_MODEL + h * DH + vdh;

    // prologue: tile 0 -> buf 0; tile 1 loads left in flight
    bf16x8 kreg = *(const bf16x8*)kbase;
    bf16x8 vreg = *(const bf16x8*)vbase;
    *(bf16x8*)&Ks[0][kwofs] = kreg;
    #pragma unroll
    for (int i = 0; i < 8; ++i)
        Vs[0][(vdh + i) * 64 + (((vkey >> 3) ^ i) * 8) + (vkey & 7)] = vreg[i];
    if (NT > 1) {
        kreg = *(const bf16x8*)(kbase + (size_t)64 * D_MODEL);
        vreg = *(const bf16x8*)(vbase + (size_t)64 * D_MODEL);
    }
    __syncthreads();

    for (int t = 0; t < NT; ++t) {
        const int buf = t & 1;
        // write tile t+1 (regs loaded a full iteration ago) to alternate buf
        if (t + 1 < NT) {
            *(bf16x8*)&Ks[buf ^ 1][kwofs] = kreg;
            #pragma unroll
            for (int i = 0; i < 8; ++i)
                Vs[buf ^ 1][(vdh + i) * 64 + (((vkey >> 3) ^ i) * 8) + (vkey & 7)] = vreg[i];
        }
        // issue tile t+2 loads; land during this tile's compute + next write
        if (t + 2 < NT) {
            kreg = *(const bf16x8*)(kbase + (size_t)(t + 2) * 64 * D_MODEL);
            vreg = *(const bf16x8*)(vbase + (size_t)(t + 2) * 64 * D_MODEL);
        }

        f32x4 st[4];
        #pragma unroll
        for (int kt = 0; kt < 4; ++kt) {
            const int kr = (kt * 16 + l15) * 64;
            bf16x8 kf0 = *(const bf16x8*)&Ks[buf][kr + krswz0];
            bf16x8 kf1 = *(const bf16x8*)&Ks[buf][kr + krswz1];
            f32x4 z = {};
            z = __builtin_amdgcn_mfma_f32_16x16x32_bf16(kf0, qf0, z, 0, 0, 0);
            z = __builtin_amdgcn_mfma_f32_16x16x32_bf16(kf1, qf1, z, 0, 0, 0);
            st[kt] = z;
        }

        float mx = st[0][0];
        #pragma unroll
        for (int kt = 0; kt < 4; ++kt)
            #pragma unroll
            for (int r = 0; r < 4; ++r)
                mx = fmaxf(mx, st[kt][r]);
        mx = fmaxf(mx, __shfl_xor(mx, 16));
        mx = fmaxf(mx, __shfl_xor(mx, 32));

        if (!__all(mx <= m_run + thr)) {
            const float mnew  = fmaxf(m_run, mx);
            const float alpha = __builtin_amdgcn_exp2f((m_run - mnew) * csc);
            m_run = mnew;
            l_run *= alpha;
            float a[4];
            #pragma unroll
            for (int r = 0; r < 4; ++r)
                a[r] = __shfl(alpha, (lane & 48) | (quad * 4 + r));
            #pragma unroll
            for (int dt = 0; dt < 4; ++dt)
                #pragma unroll
                for (int r = 0; r < 4; ++r)
                    o[dt][r] *= a[r];
        }

        float rs = 0.f;
        #pragma unroll
        for (int kt = 0; kt < 4; ++kt) {
            float p0 = __builtin_amdgcn_exp2f((st[kt][0] - m_run) * csc);
            float p1 = __builtin_amdgcn_exp2f((st[kt][1] - m_run) * csc);
            float p2 = __builtin_amdgcn_exp2f((st[kt][2] - m_run) * csc);
            float p3 = __builtin_amdgcn_exp2f((st[kt][3] - m_run) * csc);
            rs += (p0 + p1) + (p2 + p3);
            uint2 pk;
            pk.x = (uint32_t)f2bf(p0) | ((uint32_t)f2bf(p1) << 16);
            pk.y = (uint32_t)f2bf(p2) | ((uint32_t)f2bf(p3) << 16);
            const int G = kt * 2 + (quad >> 1);
            *(uint2*)&Ps[w][l15 * 64 + ((G ^ (l15 & 7)) * 8) + (quad & 1) * 4] = pk;
        }
        rs += __shfl_xor(rs, 16);
        rs += __shfl_xor(rs, 32);
        l_run += rs;

        #pragma unroll
        for (int f = 0; f < 2; ++f) {
            bf16x8 pf = *(const bf16x8*)&Ps[w][l15 * 64 + (((f * 4 + quad) ^ (l15 & 7)) * 8)];
            #pragma unroll
            for (int dt = 0; dt < 4; ++dt) {
                bf16x8 vf = *(const bf16x8*)&Vs[buf][(dt * 16 + l15) * 64 + (((f * 4 + quad) ^ (l15 & 7)) * 8)];
                o[dt] = __builtin_amdgcn_mfma_f32_16x16x32_bf16(pf, vf, o[dt], 0, 0, 0);
            }
        }

        __syncthreads();   // single barrier per tile
    }

    const float inv = 1.f / l_run;
    #pragma unroll
    for (int r = 0; r < 4; ++r) {
        const float linv = __shfl(inv, (lane & 48) | (quad * 4 + r));
        const int row = q0 + w * 16 + quad * 4 + r;
        #pragma unroll
        for (int dt = 0; dt < 4; ++dt) {
            int col = h * DH + dt * 16 + l15;
            Ow[(size_t)row * D_MODEL + col] = (short)f2bf(o[dt][r] * linv);
        }
    }
}

extern "C" void kernel_launch(void* const* d_in, const int* in_sizes, int n_in,
                              void* d_out, int out_size, void* d_ws, size_t ws_size,
                              hipStream_t stream) {
    const float* Q   = (const float*)d_in[0];
    const float* K   = (const float*)d_in[1];
    const float* V   = (const float*)d_in[2];
    const float* w_q = (const float*)d_in[3];
    const float* b_q = (const float*)d_in[4];
    const float* w_k = (const float*)d_in[5];
    const float* b_k = (const float*)d_in[6];
    const float* w_v = (const float*)d_in[7];
    const float* b_v = (const float*)d_in[8];
    const float* w_o = (const float*)d_in[9];
    const float* b_o = (const float*)d_in[10];
    float* out = (float*)d_out;

    const int L = in_sizes[0] / D_MODEL;   // 4096
    const size_t mat = (size_t)L * D_MODEL;

    // Memory plan (d_ws known-safe at 24 MB; d_out = 16 MB fp32):
    //   d_ws  [0, 8MB): Wb   — 4 bf16 weight matrices (wq,wk,wv,wo)
    //   d_ws  [8,16MB): a_ws — attention output (bf16)
    //   d_ws [16,24MB): v_ws — projected V (bf16)
    //   d_out [0, 8MB): q_ws; d_out [8,16MB): k_ws — dead before out_proj
    //   writes fp32 C over all of d_out (stream-ordered; fully rewritten).
    ushort* Wb   = (ushort*)d_ws;
    ushort* a_ws = (ushort*)d_ws + 4 * 1048576;
    ushort* v_ws = a_ws + mat;
    ushort* q_ws = (ushort*)d_out;
    ushort* k_ws = q_ws + mat;

    cvt_w_kernel<<<dim3(2048), dim3(256), 0, stream>>>(w_q, w_k, w_v, w_o, Wb);

    dim3 gqkv(D_MODEL / 128, L / 128, 3);
    qkv_proj_kernel<<<gqkv, dim3(256), 0, stream>>>(Q, K, V, Wb, b_q, b_k, b_v,
                                                    q_ws, k_ws, v_ws, L);
    dim3 gattn(L / 128, NHEAD);
    attn_kernel<<<gattn, dim3(512), 0, stream>>>(q_ws, k_ws, v_ws, a_ws, L);
    dim3 gout(D_MODEL / 128, L / 128);
    out_proj_kernel<<<gout, dim3(256), 0, stream>>>(a_ws, Wb, b_o, out, L);
}

// Round 3
// 301.813 us; speedup vs baseline: 1.0854x; 1.0532x over previous
//
#include <hip/hip_runtime.h>
#include <hip/hip_bf16.h>
#include <stdint.h>

#define D_MODEL 1024
#define NHEAD   16
#define DH      64

typedef __attribute__((ext_vector_type(8))) short bf16x8;
typedef __attribute__((ext_vector_type(4))) float f32x4;

__device__ __forceinline__ ushort f2bf(float f) {
    __hip_bfloat16 h = __float2bfloat16(f);
    return *reinterpret_cast<ushort*>(&h);
}

__device__ __forceinline__ void gload_lds16(const void* g, void* l) {
    __builtin_amdgcn_global_load_lds(
        (const __attribute__((address_space(1))) void*)g,
        (__attribute__((address_space(3))) void*)l, 16, 0, 0);
}

// Load 8 contiguous fp32, convert to bf16x8 in-register.
__device__ __forceinline__ bf16x8 load8f(const float* p) {
    const float4 a = *(const float4*)p;
    const float4 b = *(const float4*)(p + 4);
    bf16x8 r;
    r[0] = (short)f2bf(a.x); r[1] = (short)f2bf(a.y);
    r[2] = (short)f2bf(a.z); r[3] = (short)f2bf(a.w);
    r[4] = (short)f2bf(b.x); r[5] = (short)f2bf(b.y);
    r[6] = (short)f2bf(b.z); r[7] = (short)f2bf(b.w);
    return r;
}

// fp32 -> bf16 weight conversion: 4 matrices of 1M elements each.
__global__ __launch_bounds__(256) void cvt_w_kernel(
    const float* __restrict__ w0, const float* __restrict__ w1,
    const float* __restrict__ w2, const float* __restrict__ w3,
    ushort* __restrict__ out)
{
    const int g = blockIdx.x * 256 + threadIdx.x;   // group of 8 elems
    const int m = g >> 17;                          // 131072 groups / matrix
    const int off = (g & 131071) * 8;
    const float* src = (m == 0) ? w0 : (m == 1) ? w1 : (m == 2) ? w2 : w3;
    *(bf16x8*)(out + (size_t)m * 1048576 + off) = load8f(src + off);
}

// ---- shared GEMM epilogue helpers ----
__device__ __forceinline__ void storeC(float*  C, size_t i, float v) { C[i] = v; }
__device__ __forceinline__ void storeC(ushort* C, size_t i, float v) { C[i] = (short)f2bf(v); }

// C = scale * (X(MxK) @ Wb^T + bias). Wb is NxK bf16.
// A_F32: X fp32 (explicit reg staging + convert); else bf16 via global_load_lds.
// R0 2-barrier structure (proven best vs 2-phase pipeline, R1 post-mortem).
// NW = waves per block: 4 (2x2 wave grid, 64x64/wave) or 8 (2x4, 64x32/wave —
// used by out_proj to double resident waves/CU and hide staging latency).
// XCD swizzle: each XCD owns contiguous m-rows x all n-cols (L2 locality).
template<int NW, bool A_F32, typename TX, typename TOUT>
__device__ __forceinline__ void gemm_core(
    const TX* __restrict__ X,
    const ushort* __restrict__ Wb,
    const float* __restrict__ Bias,
    TOUT* __restrict__ C,
    int M, int N, int K, float scale,
    short* As, short* Bs)
{
    const int tid  = threadIdx.x;
    const int w    = tid >> 6;
    const int lane = tid & 63;
    const int quad = lane >> 4;
    const int l15  = lane & 15;
    const int wr   = (NW == 4) ? (w >> 1) : (w >> 2);
    const int wc   = (NW == 4) ? (w & 1)  : (w & 3);
    const int NJ   = (NW == 4) ? 4 : 2;          // 16-col fragments per wave
    const int colw = (NW == 4) ? 64 : 32;        // cols per wave

    // XCD swizzle (bijective; identity if shape doesn't fit)
    int bx = blockIdx.x, by = blockIdx.y;
    if (gridDim.x == 8 && (gridDim.y & 7) == 0) {
        const int fid   = by * 8 + bx;
        const int xcd   = fid & 7;
        const int local = fid >> 3;
        const int rpx   = gridDim.y >> 3;
        by = xcd * rpx + (local >> 3);
        bx = local & 7;
    }
    const int m0 = by * 128;
    const int n0 = bx * 128;

    f32x4 acc[4][4] = {};

    for (int k0 = 0; k0 < K; k0 += 32) {
        __syncthreads();   // WAR on LDS tiles
        // B-tile: 8 chunks of 1 KB, DMA direct to LDS.
        #pragma unroll
        for (int c = 0; c < 8 / NW; ++c) {
            int chunk = w * (8 / NW) + c;
            int row   = chunk * 16 + (lane >> 2);
            gload_lds16(Wb + (size_t)(n0 + row) * K + k0 + (lane & 3) * 8,
                        &Bs[chunk * 512]);
        }
        // A-tile
        if constexpr (A_F32) {
            #pragma unroll
            for (int c = 0; c < 2; ++c) {
                int idx = c * 256 + tid;
                int row = idx >> 2;
                int col = (idx & 3) * 8;
                *(bf16x8*)&As[row * 32 + col] =
                    load8f((const float*)X + (size_t)(m0 + row) * K + k0 + col);
            }
        } else {
            #pragma unroll
            for (int c = 0; c < 8 / NW; ++c) {
                int chunk = w * (8 / NW) + c;
                int row   = chunk * 16 + (lane >> 2);
                gload_lds16((const ushort*)X + (size_t)(m0 + row) * K + k0 + (lane & 3) * 8,
                            &As[chunk * 512]);
            }
        }
        __syncthreads();   // drains vmcnt (DMA) + lgkmcnt before use

        bf16x8 af[4], bfr[4];
        #pragma unroll
        for (int i = 0; i < 4; ++i)
            af[i] = *(const bf16x8*)&As[(wr * 64 + i * 16 + l15) * 32 + quad * 8];
        #pragma unroll
        for (int j = 0; j < NJ; ++j)
            bfr[j] = *(const bf16x8*)&Bs[(wc * colw + j * 16 + l15) * 32 + quad * 8];
        #pragma unroll
        for (int i = 0; i < 4; ++i)
            #pragma unroll
            for (int j = 0; j < NJ; ++j)
                acc[i][j] = __builtin_amdgcn_mfma_f32_16x16x32_bf16(af[i], bfr[j], acc[i][j], 0, 0, 0);
    }

    float bias[4];
    #pragma unroll
    for (int j = 0; j < NJ; ++j)
        bias[j] = Bias[n0 + wc * colw + j * 16 + l15];

    #pragma unroll
    for (int i = 0; i < 4; ++i) {
        int row = m0 + wr * 64 + i * 16 + quad * 4;
        #pragma unroll
        for (int j = 0; j < NJ; ++j) {
            int col = n0 + wc * colw + j * 16 + l15;
            #pragma unroll
            for (int r = 0; r < 4; ++r)
                storeC(C, (size_t)(row + r) * N + col, (acc[i][j][r] + bias[j]) * scale);
        }
    }
}

__global__ __launch_bounds__(256) void qkv_proj_kernel(
    const float* __restrict__ Qin, const float* __restrict__ Kin,
    const float* __restrict__ Vin,
    const ushort* __restrict__ Wb,
    const float* __restrict__ Bq, const float* __restrict__ Bk,
    const float* __restrict__ Bv,
    ushort* qo, ushort* ko, ushort* vo, int L)
{
    __shared__ short As[4096];
    __shared__ short Bs[4096];
    const int z = blockIdx.z;
    const float *X, *B; ushort* C;
    // Q output is pre-scaled by csc = 1/8 * log2(e): scores arrive in the
    // exp2 domain, removing a v_mul per score element in the attn loop.
    float scale = 1.0f;
    if (z == 0)      { X = Qin; B = Bq; C = qo; scale = 0.125f * 1.44269504088896f; }
    else if (z == 1) { X = Kin; B = Bk; C = ko; }
    else             { X = Vin; B = Bv; C = vo; }
    gemm_core<4, true, float, ushort>(X, Wb + (size_t)z * 1048576, B, C,
                                      L, D_MODEL, D_MODEL, scale, As, Bs);
}

__global__ __launch_bounds__(512) void out_proj_kernel(
    const ushort* __restrict__ Xa, const ushort* __restrict__ Wb,
    const float* __restrict__ Bo, float* out, int L)
{
    __shared__ short As[4096];
    __shared__ short Bs[4096];
    gemm_core<8, false, ushort, float>(Xa, Wb + (size_t)3 * 1048576, Bo, out,
                                       L, D_MODEL, D_MODEL, 1.0f, As, Bs);
}

// Flash attention, transposed-score form. R1 structure (2 barriers/tile,
// reg-prefetch T14, defer-max T13) — R2's single-barrier dbuf regressed,
// reverted. R3: scores pre-scaled at projection (exp2 domain direct).
__global__ __launch_bounds__(512) void attn_kernel(
    const ushort* __restrict__ Qw,
    const ushort* __restrict__ Kw,
    const ushort* __restrict__ Vw,
    ushort* __restrict__ Ow, int L)
{
    __shared__ short Ks[64 * 64];
    __shared__ short Vs[64 * 64];
    __shared__ short Ps[8][16 * 64];

    const int tid  = threadIdx.x;
    const int w    = tid >> 6;
    const int lane = tid & 63;
    const int quad = lane >> 4;
    const int l15  = lane & 15;
    const int h    = blockIdx.y;
    const int q0   = blockIdx.x * 128;

    const ushort* qp = Qw + (size_t)(q0 + w * 16 + l15) * D_MODEL + h * DH + quad * 8;
    bf16x8 qf0 = *(const bf16x8*)(qp);
    bf16x8 qf1 = *(const bf16x8*)(qp + 32);

    const int kkey = tid >> 3;
    const int kc8  = tid & 7;
    const int vkey = lane;
    const int vdh  = w * 8;

    const int krswz0 = ((quad    ) ^ (l15 & 7)) * 8;
    const int krswz1 = ((quad + 4) ^ (l15 & 7)) * 8;

    f32x4 o[4] = {};
    float m_run = -3e38f, l_run = 0.f;
    // scores are already in exp2 domain (Q pre-scaled by 1/8*log2e)
    const float thr = 8.0f;   // defer-max threshold

    // prefetch tile 0 into regs
    const ushort* kptr = Kw + (size_t)kkey * D_MODEL + h * DH + kc8 * 8;
    const ushort* vptr = Vw + (size_t)vkey * D_MODEL + h * DH + vdh;
    bf16x8 kreg = *(const bf16x8*)kptr;
    bf16x8 vreg = *(const bf16x8*)vptr;

    for (int key0 = 0; key0 < L; key0 += 64) {
        __syncthreads();   // WAR: previous tile's LDS reads done
        *(bf16x8*)&Ks[kkey * 64 + ((kc8 ^ (kkey & 7)) * 8)] = kreg;
        #pragma unroll
        for (int i = 0; i < 8; ++i)
            Vs[(vdh + i) * 64 + (((vkey >> 3) ^ i) * 8) + (vkey & 7)] = vreg[i];
        __syncthreads();

        if (key0 + 64 < L) {        // issue next tile's loads; land during compute
            kptr += (size_t)64 * D_MODEL;
            vptr += (size_t)64 * D_MODEL;
            kreg = *(const bf16x8*)kptr;
            vreg = *(const bf16x8*)vptr;
        }

        f32x4 st[4];
        #pragma unroll
        for (int kt = 0; kt < 4; ++kt) {
            const int kr = (kt * 16 + l15) * 64;
            bf16x8 kf0 = *(const bf16x8*)&Ks[kr + krswz0];
            bf16x8 kf1 = *(const bf16x8*)&Ks[kr + krswz1];
            f32x4 z = {};
            z = __builtin_amdgcn_mfma_f32_16x16x32_bf16(kf0, qf0, z, 0, 0, 0);
            z = __builtin_amdgcn_mfma_f32_16x16x32_bf16(kf1, qf1, z, 0, 0, 0);
            st[kt] = z;
        }

        float mx = st[0][0];
        #pragma unroll
        for (int kt = 0; kt < 4; ++kt)
            #pragma unroll
            for (int r = 0; r < 4; ++r)
                mx = fmaxf(mx, st[kt][r]);
        mx = fmaxf(mx, __shfl_xor(mx, 16));
        mx = fmaxf(mx, __shfl_xor(mx, 32));

        if (!__all(mx <= m_run + thr)) {
            const float mnew  = fmaxf(m_run, mx);
            const float alpha = __builtin_amdgcn_exp2f(m_run - mnew);
            m_run = mnew;
            l_run *= alpha;
            float a[4];
            #pragma unroll
            for (int r = 0; r < 4; ++r)
                a[r] = __shfl(alpha, (lane & 48) | (quad * 4 + r));
            #pragma unroll
            for (int dt = 0; dt < 4; ++dt)
                #pragma unroll
                for (int r = 0; r < 4; ++r)
                    o[dt][r] *= a[r];
        }

        float rs = 0.f;
        #pragma unroll
        for (int kt = 0; kt < 4; ++kt) {
            float p0 = __builtin_amdgcn_exp2f(st[kt][0] - m_run);
            float p1 = __builtin_amdgcn_exp2f(st[kt][1] - m_run);
            float p2 = __builtin_amdgcn_exp2f(st[kt][2] - m_run);
            float p3 = __builtin_amdgcn_exp2f(st[kt][3] - m_run);
            rs += (p0 + p1) + (p2 + p3);
            uint2 pk;
            pk.x = (uint32_t)f2bf(p0) | ((uint32_t)f2bf(p1) << 16);
            pk.y = (uint32_t)f2bf(p2) | ((uint32_t)f2bf(p3) << 16);
            const int G = kt * 2 + (quad >> 1);
            *(uint2*)&Ps[w][l15 * 64 + ((G ^ (l15 & 7)) * 8) + (quad & 1) * 4] = pk;
        }
        rs += __shfl_xor(rs, 16);
        rs += __shfl_xor(rs, 32);
        l_run += rs;

        #pragma unroll
        for (int f = 0; f < 2; ++f) {
            bf16x8 pf = *(const bf16x8*)&Ps[w][l15 * 64 + (((f * 4 + quad) ^ (l15 & 7)) * 8)];
            #pragma unroll
            for (int dt = 0; dt < 4; ++dt) {
                bf16x8 vf = *(const bf16x8*)&Vs[(dt * 16 + l15) * 64 + (((f * 4 + quad) ^ (l15 & 7)) * 8)];
                o[dt] = __builtin_amdgcn_mfma_f32_16x16x32_bf16(pf, vf, o[dt], 0, 0, 0);
            }
        }
    }

    const float inv = 1.f / l_run;
    #pragma unroll
    for (int r = 0; r < 4; ++r) {
        const float linv = __shfl(inv, (lane & 48) | (quad * 4 + r));
        const int row = q0 + w * 16 + quad * 4 + r;
        #pragma unroll
        for (int dt = 0; dt < 4; ++dt) {
            int col = h * DH + dt * 16 + l15;
            Ow[(size_t)row * D_MODEL + col] = (short)f2bf(o[dt][r] * linv);
        }
    }
}

extern "C" void kernel_launch(void* const* d_in, const int* in_sizes, int n_in,
                              void* d_out, int out_size, void* d_ws, size_t ws_size,
                              hipStream_t stream) {
    const float* Q   = (const float*)d_in[0];
    const float* K   = (const float*)d_in[1];
    const float* V   = (const float*)d_in[2];
    const float* w_q = (const float*)d_in[3];
    const float* b_q = (const float*)d_in[4];
    const float* w_k = (const float*)d_in[5];
    const float* b_k = (const float*)d_in[6];
    const float* w_v = (const float*)d_in[7];
    const float* b_v = (const float*)d_in[8];
    const float* w_o = (const float*)d_in[9];
    const float* b_o = (const float*)d_in[10];
    float* out = (float*)d_out;

    const int L = in_sizes[0] / D_MODEL;   // 4096
    const size_t mat = (size_t)L * D_MODEL;

    // Memory plan (d_ws known-safe at 24 MB; d_out = 16 MB fp32):
    //   d_ws  [0, 8MB): Wb   — 4 bf16 weight matrices (wq,wk,wv,wo)
    //   d_ws  [8,16MB): a_ws — attention output (bf16)
    //   d_ws [16,24MB): v_ws — projected V (bf16)
    //   d_out [0, 8MB): q_ws; d_out [8,16MB): k_ws — dead before out_proj
    //   writes fp32 C over all of d_out (stream-ordered; fully rewritten).
    ushort* Wb   = (ushort*)d_ws;
    ushort* a_ws = (ushort*)d_ws + 4 * 1048576;
    ushort* v_ws = a_ws + mat;
    ushort* q_ws = (ushort*)d_out;
    ushort* k_ws = q_ws + mat;

    cvt_w_kernel<<<dim3(2048), dim3(256), 0, stream>>>(w_q, w_k, w_v, w_o, Wb);

    dim3 gqkv(D_MODEL / 128, L / 128, 3);
    qkv_proj_kernel<<<gqkv, dim3(256), 0, stream>>>(Q, K, V, Wb, b_q, b_k, b_v,
                                                    q_ws, k_ws, v_ws, L);
    dim3 gattn(L / 128, NHEAD);
    attn_kernel<<<gattn, dim3(512), 0, stream>>>(q_ws, k_ws, v_ws, a_ws, L);
    dim3 gout(D_MODEL / 128, L / 128);
    out_proj_kernel<<<gout, dim3(512), 0, stream>>>(a_ws, Wb, b_o, out, L);
}